// Round 1
// baseline (1646.258 us; speedup 1.0000x reference)
//
#include <hip/hip_runtime.h>
#include <hip/hip_bf16.h>
#include <math.h>

#define N_NODES 16384
#define E_EDGES 524288
#define E_TOT   (E_EDGES + N_NODES)   // 540672
#define HDIM    512                   // HEADS * OUT_CH
#define SLOPE   0.2f

// ---------------------------------------------------------------------------
// edge_index storage-width detection (int64 per reference vs int32 per harness)
// values are in [0,16384) so if stored int64, every high 32-bit word is 0.
__global__ void detect_kernel(const void* __restrict__ ei, int* __restrict__ flag) {
    int t = threadIdx.x;
    int v = ((const int*)ei)[2 * t + 1];  // odd 32-bit words of first 64 entries
    unsigned long long b = __ballot(v != 0);
    if (t == 0) *flag = (b == 0ULL) ? 1 : 0;  // 1 -> int64 storage
}

__device__ __forceinline__ int edge_val(const void* ei, int idx, int is64) {
    if (is64) return (int)((const long long*)ei)[idx];
    return ((const int*)ei)[idx];
}

// ---------------------------------------------------------------------------
// CSR build
__global__ __launch_bounds__(256) void count_kernel(const void* __restrict__ ei,
                                                    const int* __restrict__ flag,
                                                    int* __restrict__ deg) {
    int e = blockIdx.x * 256 + threadIdx.x;
    if (e >= E_TOT) return;
    int is64 = *flag;
    int dst = (e < E_EDGES) ? edge_val(ei, E_EDGES + e, is64) : (e - E_EDGES);
    atomicAdd(&deg[dst], 1);
}

__global__ __launch_bounds__(1024) void scan_kernel(const int* __restrict__ deg,
                                                    int* __restrict__ rowptr,
                                                    int* __restrict__ cursor) {
    __shared__ int ps[1024];
    int tid = threadIdx.x;
    int base = tid * 16;
    int loc[16];
    int s = 0;
#pragma unroll
    for (int i = 0; i < 16; ++i) { loc[i] = deg[base + i]; s += loc[i]; }
    ps[tid] = s;
    __syncthreads();
    for (int off = 1; off < 1024; off <<= 1) {
        int t = (tid >= off) ? ps[tid - off] : 0;
        __syncthreads();
        if (tid >= off) ps[tid] += t;
        __syncthreads();
    }
    int run = ps[tid] - s;  // exclusive prefix
#pragma unroll
    for (int i = 0; i < 16; ++i) {
        rowptr[base + i] = run;
        cursor[base + i] = run;
        run += loc[i];
    }
    if (tid == 1023) rowptr[N_NODES] = run;
}

__global__ __launch_bounds__(256) void fill_kernel(const void* __restrict__ ei,
                                                   const int* __restrict__ flag,
                                                   int* __restrict__ cursor,
                                                   int* __restrict__ col) {
    int e = blockIdx.x * 256 + threadIdx.x;
    if (e >= E_TOT) return;
    int is64 = *flag;
    int src, dst;
    if (e < E_EDGES) {
        src = edge_val(ei, e, is64);
        dst = edge_val(ei, E_EDGES + e, is64);
    } else {
        src = dst = e - E_EDGES;
    }
    int slot = atomicAdd(&cursor[dst], 1);
    col[slot] = src;
}

// ---------------------------------------------------------------------------
// fp32 GEMM  C[M,N] = A[M,K] * B[N,K]^T  (+bias, relu).  BM=BN=128, BK=16.
template <bool RELU, bool BIAS>
__global__ __launch_bounds__(256) void gemm128(const float* __restrict__ A,
                                               const float* __restrict__ B,
                                               const float* __restrict__ bias,
                                               float* __restrict__ C,
                                               int M, int N, int K) {
    __shared__ float As[16][132];
    __shared__ float Bs[16][132];
    int tid = threadIdx.x;
    int tx = tid & 15, ty = tid >> 4;
    int bm0 = blockIdx.y * 128, bn0 = blockIdx.x * 128;

    float acc[8][8];
#pragma unroll
    for (int i = 0; i < 8; ++i)
#pragma unroll
        for (int j = 0; j < 8; ++j) acc[i][j] = 0.f;

    for (int k0 = 0; k0 < K; k0 += 16) {
        float4 av[2], bv[2];
#pragma unroll
        for (int l = 0; l < 2; ++l) {
            int idx = l * 256 + tid;          // 512 float4 slots per tile
            int row = idx >> 2, k4 = idx & 3;
            av[l] = *(const float4*)&A[(size_t)(bm0 + row) * K + k0 + k4 * 4];
            bv[l] = *(const float4*)&B[(size_t)(bn0 + row) * K + k0 + k4 * 4];
        }
        __syncthreads();
#pragma unroll
        for (int l = 0; l < 2; ++l) {
            int idx = l * 256 + tid;
            int row = idx >> 2, k4 = idx & 3;
            As[k4 * 4 + 0][row] = av[l].x;
            As[k4 * 4 + 1][row] = av[l].y;
            As[k4 * 4 + 2][row] = av[l].z;
            As[k4 * 4 + 3][row] = av[l].w;
            Bs[k4 * 4 + 0][row] = bv[l].x;
            Bs[k4 * 4 + 1][row] = bv[l].y;
            Bs[k4 * 4 + 2][row] = bv[l].z;
            Bs[k4 * 4 + 3][row] = bv[l].w;
        }
        __syncthreads();
#pragma unroll
        for (int kk = 0; kk < 16; ++kk) {
            float4 a0 = *(const float4*)&As[kk][ty * 8];
            float4 a1 = *(const float4*)&As[kk][ty * 8 + 4];
            float4 b0 = *(const float4*)&Bs[kk][tx * 8];
            float4 b1 = *(const float4*)&Bs[kk][tx * 8 + 4];
            float a[8] = {a0.x, a0.y, a0.z, a0.w, a1.x, a1.y, a1.z, a1.w};
            float b[8] = {b0.x, b0.y, b0.z, b0.w, b1.x, b1.y, b1.z, b1.w};
#pragma unroll
            for (int i = 0; i < 8; ++i)
#pragma unroll
                for (int j = 0; j < 8; ++j) acc[i][j] = fmaf(a[i], b[j], acc[i][j]);
        }
        __syncthreads();
    }

    float bvv[8];
#pragma unroll
    for (int j = 0; j < 8; ++j) bvv[j] = BIAS ? bias[bn0 + tx * 8 + j] : 0.f;

#pragma unroll
    for (int i = 0; i < 8; ++i) {
        int row = bm0 + ty * 8 + i;
        float v[8];
#pragma unroll
        for (int j = 0; j < 8; ++j) {
            v[j] = acc[i][j] + bvv[j];
            if (RELU) v[j] = fmaxf(v[j], 0.f);
        }
        float* cp = &C[(size_t)row * N + bn0 + tx * 8];
        *(float4*)cp = make_float4(v[0], v[1], v[2], v[3]);
        *(float4*)(cp + 4) = make_float4(v[4], v[5], v[6], v[7]);
    }
}

// ---------------------------------------------------------------------------
// attention logits a_src[n,h], a_dst[n,h]
__global__ __launch_bounds__(256) void attn_kernel(const float* __restrict__ h,
                                                   const float* __restrict__ att_src,
                                                   const float* __restrict__ att_dst,
                                                   float* __restrict__ a_src,
                                                   float* __restrict__ a_dst) {
    int n = blockIdx.x, tid = threadIdx.x;
    float h0 = h[(size_t)n * HDIM + tid];
    float h1 = h[(size_t)n * HDIM + 256 + tid];
    __shared__ float4 red[256];
    red[tid] = make_float4(h0 * att_src[tid], h1 * att_src[256 + tid],
                           h0 * att_dst[tid], h1 * att_dst[256 + tid]);
    __syncthreads();
    for (int off = 128; off > 0; off >>= 1) {
        if (tid < off) {
            float4 o = red[tid + off];
            float4 m = red[tid];
            m.x += o.x; m.y += o.y; m.z += o.z; m.w += o.w;
            red[tid] = m;
        }
        __syncthreads();
    }
    if (tid == 0) {
        float4 r = red[0];
        a_src[2 * n] = r.x; a_src[2 * n + 1] = r.y;
        a_dst[2 * n] = r.z; a_dst[2 * n + 1] = r.w;
    }
}

__device__ __forceinline__ float lrelu(float x) {
    return fmaxf(x, 0.f) + SLOPE * fminf(x, 0.f);
}

// ---------------------------------------------------------------------------
// per-dst-node segment softmax + weighted aggregation; writes relu(agg+bias)
__global__ __launch_bounds__(256) void aggregate_kernel(const float* __restrict__ h,
                                                        const float* __restrict__ a_src,
                                                        const float* __restrict__ a_dst,
                                                        const int* __restrict__ rowptr,
                                                        const int* __restrict__ col,
                                                        const float* __restrict__ conv_b,
                                                        float* __restrict__ act0) {
    int n = blockIdx.x, tid = threadIdx.x;
    int rs = rowptr[n], re = rowptr[n + 1];
    float ad0 = a_dst[2 * n], ad1 = a_dst[2 * n + 1];
    __shared__ float r0[256], r1[256];

    // pass 1: segment max
    float m0 = -1e30f, m1 = -1e30f;
    for (int k = rs + tid; k < re; k += 256) {
        int s = col[k];
        float e0 = lrelu(a_src[2 * s] + ad0);
        float e1 = lrelu(a_src[2 * s + 1] + ad1);
        m0 = fmaxf(m0, e0); m1 = fmaxf(m1, e1);
    }
    r0[tid] = m0; r1[tid] = m1;
    __syncthreads();
    for (int off = 128; off > 0; off >>= 1) {
        if (tid < off) {
            r0[tid] = fmaxf(r0[tid], r0[tid + off]);
            r1[tid] = fmaxf(r1[tid], r1[tid + off]);
        }
        __syncthreads();
    }
    float M0 = r0[0], M1 = r1[0];
    __syncthreads();

    // pass 2: sum of exp
    float s0 = 0.f, s1 = 0.f;
    for (int k = rs + tid; k < re; k += 256) {
        int s = col[k];
        float e0 = lrelu(a_src[2 * s] + ad0);
        float e1 = lrelu(a_src[2 * s + 1] + ad1);
        s0 += expf(e0 - M0); s1 += expf(e1 - M1);
    }
    r0[tid] = s0; r1[tid] = s1;
    __syncthreads();
    for (int off = 128; off > 0; off >>= 1) {
        if (tid < off) {
            r0[tid] += r0[tid + off];
            r1[tid] += r1[tid + off];
        }
        __syncthreads();
    }
    float inv0 = 1.f / r0[0], inv1 = 1.f / r1[0];
    __syncthreads();

    // pass 3: chunked alpha-weighted channel accumulation
    __shared__ float al0[256], al1[256];
    __shared__ int sc[256];
    float acc0 = 0.f, acc1 = 0.f;
    for (int base = rs; base < re; base += 256) {
        int len = min(256, re - base);
        if (tid < len) {
            int s = col[base + tid];
            sc[tid] = s;
            float e0 = lrelu(a_src[2 * s] + ad0);
            float e1 = lrelu(a_src[2 * s + 1] + ad1);
            al0[tid] = expf(e0 - M0) * inv0;
            al1[tid] = expf(e1 - M1) * inv1;
        }
        __syncthreads();
        for (int kk = 0; kk < len; ++kk) {
            const float* hr = h + (size_t)sc[kk] * HDIM;
            acc0 = fmaf(al0[kk], hr[tid], acc0);
            acc1 = fmaf(al1[kk], hr[tid + 256], acc1);
        }
        __syncthreads();
    }
    act0[(size_t)n * HDIM + tid] = fmaxf(acc0 + conv_b[tid], 0.f);
    act0[(size_t)n * HDIM + 256 + tid] = fmaxf(acc1 + conv_b[tid + 256], 0.f);
}

// ---------------------------------------------------------------------------
// fused MLP tail: 128 ->(relu) 64 ->(relu) 32 ->(none after W4) 3
__global__ __launch_bounds__(256) void mlp_tail_kernel(const float* __restrict__ act2,
                                                       const float* __restrict__ W2, const float* __restrict__ b2,
                                                       const float* __restrict__ W3, const float* __restrict__ b3,
                                                       const float* __restrict__ W4, const float* __restrict__ b4,
                                                       float* __restrict__ p) {
    __shared__ float w2[64][129];
    __shared__ float w3[32][65];
    __shared__ float w4[3][33];
    __shared__ float bb2[64], bb3[32], bb4[3];
    __shared__ float xb[4][128];
    __shared__ float yb[4][64];
    __shared__ float zb[4][32];
    int tid = threadIdx.x;
    for (int idx = tid; idx < 64 * 128; idx += 256) w2[idx >> 7][idx & 127] = W2[idx];
    for (int idx = tid; idx < 32 * 64; idx += 256) w3[idx >> 6][idx & 63] = W3[idx];
    for (int idx = tid; idx < 96; idx += 256) w4[idx / 32][idx % 32] = W4[idx];
    if (tid < 64) bb2[tid] = b2[tid];
    if (tid < 32) bb3[tid] = b3[tid];
    if (tid < 3) bb4[tid] = b4[tid];
    __syncthreads();

    int n0 = blockIdx.x * 64;
    int nl = tid >> 6, lane = tid & 63;
    for (int g = 0; g < 64; g += 4) {
        for (int l = tid; l < 512; l += 256)
            xb[l >> 7][l & 127] = act2[(size_t)(n0 + g + (l >> 7)) * 128 + (l & 127)];
        __syncthreads();
        float y = bb2[lane];
#pragma unroll 8
        for (int j = 0; j < 128; ++j) y = fmaf(w2[lane][j], xb[nl][j], y);
        yb[nl][lane] = fmaxf(y, 0.f);
        __syncthreads();
        if (lane < 32) {
            float z = bb3[lane];
#pragma unroll 8
            for (int j = 0; j < 64; ++j) z = fmaf(w3[lane][j], yb[nl][j], z);
            zb[nl][lane] = fmaxf(z, 0.f);
        }
        __syncthreads();
        if (lane < 3) {
            float c = bb4[lane];
#pragma unroll
            for (int j = 0; j < 32; ++j) c = fmaf(w4[lane][j], zb[nl][j], c);
            p[(size_t)(n0 + g + nl) * 3 + lane] = c;
        }
        __syncthreads();
    }
}

// ---------------------------------------------------------------------------
// pairwise distances via direct diffs (numerically better than sq+sq-2dot)
__global__ __launch_bounds__(256) void cdist_kernel(const float* __restrict__ p,
                                                    float* __restrict__ out) {
    int tid = threadIdx.x;
    int j0 = blockIdx.x * 1024 + tid * 4;
    int i0 = blockIdx.y * 64;
    __shared__ float pi[64][3];
    for (int l = tid; l < 192; l += 256) pi[l / 3][l % 3] = p[i0 * 3 + l];
    float px[4], py[4], pz[4];
#pragma unroll
    for (int q = 0; q < 4; ++q) {
        const float* pp = p + (size_t)(j0 + q) * 3;
        px[q] = pp[0]; py[q] = pp[1]; pz[q] = pp[2];
    }
    __syncthreads();
#pragma unroll 4
    for (int i = 0; i < 64; ++i) {
        float ax = pi[i][0], ay = pi[i][1], az = pi[i][2];
        float o[4];
#pragma unroll
        for (int q = 0; q < 4; ++q) {
            float dx = ax - px[q], dy = ay - py[q], dz = az - pz[q];
            float d2 = fmaf(dx, dx, fmaf(dy, dy, dz * dz));
            o[q] = (d2 > 0.f) ? sqrtf(d2) : 0.f;
        }
        *(float4*)(out + (size_t)(i0 + i) * N_NODES + j0) = make_float4(o[0], o[1], o[2], o[3]);
    }
}

// ---------------------------------------------------------------------------
extern "C" void kernel_launch(void* const* d_in, const int* in_sizes, int n_in,
                              void* d_out, int out_size, void* d_ws, size_t ws_size,
                              hipStream_t stream) {
    const float* x       = (const float*)d_in[0];
    const void*  ei      = d_in[1];
    const float* conv_W  = (const float*)d_in[2];
    const float* att_src = (const float*)d_in[3];
    const float* att_dst = (const float*)d_in[4];
    const float* conv_b  = (const float*)d_in[5];
    const float* Wa = (const float*)d_in[6];  const float* ba = (const float*)d_in[7];
    const float* W1 = (const float*)d_in[8];  const float* b1 = (const float*)d_in[9];
    const float* W2 = (const float*)d_in[10]; const float* b2 = (const float*)d_in[11];
    const float* W3 = (const float*)d_in[12]; const float* b3 = (const float*)d_in[13];
    const float* W4 = (const float*)d_in[14]; const float* b4 = (const float*)d_in[15];
    float* out = (float*)d_out;

    // workspace layout (act1/act2/p alias h, which is dead after aggregation)
    float* ws_f  = (float*)d_ws;
    float* h     = ws_f;                          // 16384*512
    float* act0  = ws_f + (size_t)N_NODES * HDIM; // 16384*512
    float* a_src = act0 + (size_t)N_NODES * HDIM; // 16384*2
    float* a_dst = a_src + N_NODES * 2;           // 16384*2
    int* deg     = (int*)(a_dst + N_NODES * 2);   // 16384
    int* rowptr  = deg + N_NODES;                 // 16385
    int* cursor  = rowptr + N_NODES + 1;          // 16384
    int* col     = cursor + N_NODES;              // 540672
    int* flag    = col + E_TOT;                   // 1
    float* act1  = h;                             // 16384*256 (alias)
    float* act2  = h + (size_t)N_NODES * 256;     // 16384*128 (alias)
    float* p3    = act2 + (size_t)N_NODES * 128;  // 16384*3   (alias)

    hipMemsetAsync(deg, 0, N_NODES * sizeof(int), stream);
    detect_kernel<<<1, 64, 0, stream>>>(ei, flag);

    // h = x @ W^T  [16384,512]
    gemm128<false, false><<<dim3(4, 128), 256, 0, stream>>>(x, conv_W, nullptr, h,
                                                            N_NODES, 512, 256);
    attn_kernel<<<N_NODES, 256, 0, stream>>>(h, att_src, att_dst, a_src, a_dst);

    count_kernel<<<E_TOT / 256, 256, 0, stream>>>(ei, flag, deg);
    scan_kernel<<<1, 1024, 0, stream>>>(deg, rowptr, cursor);
    fill_kernel<<<E_TOT / 256, 256, 0, stream>>>(ei, flag, cursor, col);

    aggregate_kernel<<<N_NODES, 256, 0, stream>>>(h, a_src, a_dst, rowptr, col,
                                                  conv_b, act0);

    // act1 = relu(act0 @ Wa^T + ba)  [16384,256]
    gemm128<true, true><<<dim3(2, 128), 256, 0, stream>>>(act0, Wa, ba, act1,
                                                          N_NODES, 256, 512);
    // act2 = relu(act1 @ W1^T + b1)  [16384,128]
    gemm128<true, true><<<dim3(1, 128), 256, 0, stream>>>(act1, W1, b1, act2,
                                                          N_NODES, 128, 256);
    // p3 = tail MLP  [16384,3]
    mlp_tail_kernel<<<N_NODES / 64, 256, 0, stream>>>(act2, W2, b2, W3, b3, W4, b4, p3);

    // out = pairwise distances [16384,16384]
    cdist_kernel<<<dim3(16, 256), 256, 0, stream>>>(p3, out);
}